// Round 1
// baseline (505.314 us; speedup 1.0000x reference)
//
#include <hip/hip_runtime.h>

// Problem constants: B=2, S=8192, D=1024, H=16, DK=DV=64, W=Bq=128, nb=64.
// Pipeline: cvt(x->bf16) ; transpose+cvt(4 weights) ; 3x GEMM (q,k,v bf16) ;
//           sliding-window attention (MFMA, online softmax) ; GEMM -> fp32 out.
// Workspace: 32MB xb + 4x2MB W^T + 3x32MB qkv + 32MB ctx = 168MB.

typedef __bf16 bf16_t;
typedef bf16_t bf16x8 __attribute__((ext_vector_type(8)));
typedef float f32x4 __attribute__((ext_vector_type(4)));

#define LOG2E 1.44269504088896340736f

__device__ __forceinline__ f32x4 mfma16(bf16x8 a, bf16x8 b, f32x4 c) {
  return __builtin_amdgcn_mfma_f32_16x16x32_bf16(a, b, c, 0, 0, 0);
}

#define GLL16(gptr, lptr)                                                     \
  __builtin_amdgcn_global_load_lds(                                           \
      (__attribute__((address_space(1))) void*)(gptr),                        \
      (__attribute__((address_space(3))) void*)(lptr), 16, 0, 0)

// ---------------- fp32 -> bf16 convert (x) ----------------
__global__ __launch_bounds__(256) void cvt_bf16(const float* __restrict__ in,
                                                bf16_t* __restrict__ out, int n8) {
  int i = blockIdx.x * 256 + threadIdx.x;
  if (i < n8) {
    f32x4 a = *(const f32x4*)&in[(size_t)i * 8];
    f32x4 b = *(const f32x4*)&in[(size_t)i * 8 + 4];
    bf16x8 o;
#pragma unroll
    for (int j = 0; j < 4; ++j) { o[j] = (bf16_t)a[j]; o[4 + j] = (bf16_t)b[j]; }
    *(bf16x8*)&out[(size_t)i * 8] = o;
  }
}

// ---------------- weight transpose + convert: W[K][N] fp32 -> WT[N][K] bf16 ----
__global__ __launch_bounds__(256) void wtrans(const float* W0, const float* W1,
                                              const float* W2, const float* W3,
                                              bf16_t* T0, bf16_t* T1,
                                              bf16_t* T2, bf16_t* T3) {
  __shared__ float tile[32][33];
  const float* W; bf16_t* T;
  switch (blockIdx.z) {
    case 0: W = W0; T = T0; break;
    case 1: W = W1; T = T1; break;
    case 2: W = W2; T = T2; break;
    default: W = W3; T = T3; break;
  }
  int tx = threadIdx.x, ty = threadIdx.y;
  int x = blockIdx.x * 32 + tx;   // n
  int y0 = blockIdx.y * 32;       // k
#pragma unroll
  for (int i = ty; i < 32; i += 8) tile[i][tx] = W[(size_t)(y0 + i) * 1024 + x];
  __syncthreads();
  int xo = y0 + tx;               // k in T
  int yo = blockIdx.x * 32;       // n in T
#pragma unroll
  for (int i = ty; i < 32; i += 8)
    T[(size_t)(yo + i) * 1024 + xo] = (bf16_t)tile[tx][i];
}

// ---------------- GEMM: A[M,K] bf16 (row-major) x Bt[N,K] bf16 -> C[M,N] ------
// m97 structure: 128x128 tile, BK=32, global_load_lds width-16, 4 waves 2x2.
template <int OUTF>
__global__ __launch_bounds__(256) void gemm_bt(const bf16_t* __restrict__ A,
                                               const bf16_t* __restrict__ Bt,
                                               bf16_t* __restrict__ Cb,
                                               float* __restrict__ Cf,
                                               int M, int N, int K) {
  __shared__ bf16_t As[128 * 32];
  __shared__ bf16_t Bs[128 * 32];
  const int t = threadIdx.x;
  const int m0 = blockIdx.y << 7, n0 = blockIdx.x << 7;
  const int ar = t >> 2, ac = (t & 3) << 3;
  const bf16_t* Ag = A + (size_t)(m0 + ar) * K + ac;
  const bf16_t* Bg = Bt + (size_t)(n0 + ar) * K + ac;
  const size_t step64 = (size_t)64 * K;
  const int lane = t & 63;
  const int wm = ((t >> 7) & 1) << 6;
  const int wn = ((t >> 6) & 1) << 6;
  const int fr = lane & 15, fk = (lane >> 4) << 3;

  f32x4 acc[4][4] = {};
  for (int k0 = 0; k0 < K; k0 += 32) {
    GLL16(Ag + k0, &As[ar * 32 + ac]);
    GLL16(Ag + step64 + k0, &As[(ar + 64) * 32 + ac]);
    GLL16(Bg + k0, &Bs[ar * 32 + ac]);
    GLL16(Bg + step64 + k0, &Bs[(ar + 64) * 32 + ac]);
    __syncthreads();
    bf16x8 af[4], bfv[4];
#pragma unroll
    for (int i = 0; i < 4; ++i) af[i] = *(const bf16x8*)&As[(wm + i * 16 + fr) * 32 + fk];
#pragma unroll
    for (int j = 0; j < 4; ++j) bfv[j] = *(const bf16x8*)&Bs[(wn + j * 16 + fr) * 32 + fk];
#pragma unroll
    for (int i = 0; i < 4; ++i)
#pragma unroll
      for (int j = 0; j < 4; ++j) acc[i][j] = mfma16(af[i], bfv[j], acc[i][j]);
    __syncthreads();
  }
  // epilogue: C layout col=lane&15, row=(lane>>4)*4+reg
#pragma unroll
  for (int i = 0; i < 4; ++i)
#pragma unroll
    for (int j = 0; j < 4; ++j)
#pragma unroll
      for (int r = 0; r < 4; ++r) {
        int cm = m0 + wm + i * 16 + ((lane >> 4) << 2) + r;
        int cn = n0 + wn + j * 16 + fr;
        if (OUTF) Cf[(size_t)cm * N + cn] = acc[i][j][r];
        else      Cb[(size_t)cm * N + cn] = (bf16_t)acc[i][j][r];
      }
}

// ---------------- sliding-window attention ----------------
// grid (nb=64, H=16, B=2); 256 threads = 4 waves, wave w owns q rows [w*32,w*32+32)
#define SQK 72    // 64+8 bf16 pad
#define SVP 136   // 128+8 bf16 pad

__global__ __launch_bounds__(256, 2) void swa(const bf16_t* __restrict__ qb,
                                              const bf16_t* __restrict__ kb,
                                              const bf16_t* __restrict__ vb,
                                              bf16_t* __restrict__ ctx) {
  __shared__ bf16_t Qs[128 * SQK];
  __shared__ bf16_t KVs[128 * SQK];          // K tile, or V^T tile [64][SVP]
  __shared__ bf16_t Ps[4][32 * SVP];

  const int t = threadIdx.x;
  const int lane = t & 63;
  const int w = t >> 6;
  const int n = blockIdx.x, h = blockIdx.y, b = blockIdx.z;
  const size_t base = ((size_t)b * 8192) * 1024 + (size_t)h * 64;
  const int fr = lane & 15;
  const int fk = (lane >> 4) << 3;
  const int rq = (lane >> 4) << 2;

  // stage Q tile [128][64] -> Qs
#pragma unroll
  for (int it = 0; it < 4; ++it) {
    int c = it * 256 + t;
    int row = c >> 3, c8 = (c & 7) << 3;
    bf16x8 v = *(const bf16x8*)&qb[base + (size_t)(n * 128 + row) * 1024 + c8];
    *(bf16x8*)&Qs[row * SQK + c8] = v;
  }

  float mrow[2][4], lrow[2][4];
  f32x4 o[2][4] = {};
#pragma unroll
  for (int qt = 0; qt < 2; ++qt)
#pragma unroll
    for (int r = 0; r < 4; ++r) { mrow[qt][r] = -1e30f; lrow[qt][r] = 0.f; }

  const int cbeg = (n == 0) ? 1 : 0;
  const int cend = (n == 63) ? 1 : 2;
  for (int ch = cbeg; ch <= cend; ++ch) {
    const int kn = n + ch - 1;
    __syncthreads();  // protect KVs (prev V reads) and Qs (first iter)
    // stage K chunk [128][64]
#pragma unroll
    for (int it = 0; it < 4; ++it) {
      int c = it * 256 + t;
      int row = c >> 3, c8 = (c & 7) << 3;
      bf16x8 v = *(const bf16x8*)&kb[base + (size_t)(kn * 128 + row) * 1024 + c8];
      *(bf16x8*)&KVs[row * SQK + c8] = v;
    }
    __syncthreads();

    // S = Q K^T  (per wave: 32 q rows x 128 keys)
    f32x4 s[2][8];
#pragma unroll
    for (int qt = 0; qt < 2; ++qt)
#pragma unroll
      for (int kt = 0; kt < 8; ++kt) s[qt][kt] = (f32x4){0.f, 0.f, 0.f, 0.f};
    bf16x8 aq[2][2];
#pragma unroll
    for (int qt = 0; qt < 2; ++qt)
#pragma unroll
      for (int ks = 0; ks < 2; ++ks)
        aq[qt][ks] = *(const bf16x8*)&Qs[(w * 32 + qt * 16 + fr) * SQK + ks * 32 + fk];
#pragma unroll
    for (int kt = 0; kt < 8; ++kt) {
      bf16x8 b0 = *(const bf16x8*)&KVs[(kt * 16 + fr) * SQK + fk];
      bf16x8 b1 = *(const bf16x8*)&KVs[(kt * 16 + fr) * SQK + 32 + fk];
#pragma unroll
      for (int qt = 0; qt < 2; ++qt)
        s[qt][kt] = mfma16(aq[qt][1], b1, mfma16(aq[qt][0], b0, s[qt][kt]));
    }

    // scale + band mask; row max
    float pmax[2][4];
#pragma unroll
    for (int qt = 0; qt < 2; ++qt)
#pragma unroll
      for (int r = 0; r < 4; ++r) pmax[qt][r] = -3.0e38f;
#pragma unroll
    for (int qt = 0; qt < 2; ++qt)
#pragma unroll
      for (int kt = 0; kt < 8; ++kt)
#pragma unroll
        for (int r = 0; r < 4; ++r) {
          float sv = s[qt][kt][r] * 0.125f;
          int qloc = w * 32 + qt * 16 + rq + r;   // 0..127
          int kloc = kt * 16 + fr;                // 0..127
          bool valid = (ch == 1) || (ch == 0 ? (kloc >= qloc) : (kloc <= qloc));
          sv = valid ? sv : -3.0e38f;
          s[qt][kt][r] = sv;
          pmax[qt][r] = fmaxf(pmax[qt][r], sv);
        }
#pragma unroll
    for (int qt = 0; qt < 2; ++qt)
#pragma unroll
      for (int r = 0; r < 4; ++r)
#pragma unroll
        for (int d = 1; d < 16; d <<= 1)
          pmax[qt][r] = fmaxf(pmax[qt][r], __shfl_xor(pmax[qt][r], d, 64));

    // online softmax update
    float alpha[2][4], rsum[2][4];
#pragma unroll
    for (int qt = 0; qt < 2; ++qt)
#pragma unroll
      for (int r = 0; r < 4; ++r) {
        float mn = fmaxf(mrow[qt][r], pmax[qt][r]);
        alpha[qt][r] = exp2f((mrow[qt][r] - mn) * LOG2E);
        mrow[qt][r] = mn;
        rsum[qt][r] = 0.f;
      }
#pragma unroll
    for (int qt = 0; qt < 2; ++qt)
#pragma unroll
      for (int kt = 0; kt < 8; ++kt)
#pragma unroll
        for (int r = 0; r < 4; ++r) {
          float p = exp2f((s[qt][kt][r] - mrow[qt][r]) * LOG2E);
          s[qt][kt][r] = p;
          rsum[qt][r] += p;
        }
#pragma unroll
    for (int qt = 0; qt < 2; ++qt)
#pragma unroll
      for (int r = 0; r < 4; ++r) {
#pragma unroll
        for (int d = 1; d < 16; d <<= 1) rsum[qt][r] += __shfl_xor(rsum[qt][r], d, 64);
        lrow[qt][r] = lrow[qt][r] * alpha[qt][r] + rsum[qt][r];
      }
#pragma unroll
    for (int qt = 0; qt < 2; ++qt)
#pragma unroll
      for (int dt = 0; dt < 4; ++dt)
#pragma unroll
        for (int r = 0; r < 4; ++r) o[qt][dt][r] *= alpha[qt][r];

    // write P (bf16) to per-wave LDS, C-layout -> row-major
#pragma unroll
    for (int qt = 0; qt < 2; ++qt)
#pragma unroll
      for (int kt = 0; kt < 8; ++kt)
#pragma unroll
        for (int r = 0; r < 4; ++r)
          Ps[w][(qt * 16 + rq + r) * SVP + kt * 16 + fr] = (bf16_t)s[qt][kt][r];
    __syncthreads();  // K reads done; P visible (wave-local anyway)

    // stage V^T [64 dv][128 key]
#pragma unroll
    for (int it = 0; it < 4; ++it) {
      int c = it * 256 + t;
      int key = c & 127, d8 = (c >> 7) << 3;
      bf16x8 vv = *(const bf16x8*)&vb[base + (size_t)(kn * 128 + key) * 1024 + d8];
#pragma unroll
      for (int j = 0; j < 8; ++j) KVs[(d8 + j) * SVP + key] = vv[j];
    }
    __syncthreads();

    // O += P V  (reduction over 128 keys, 4 MFMA K-steps)
#pragma unroll
    for (int ks = 0; ks < 4; ++ks) {
      bf16x8 a0 = *(const bf16x8*)&Ps[w][(fr)*SVP + ks * 32 + fk];
      bf16x8 a1 = *(const bf16x8*)&Ps[w][(16 + fr) * SVP + ks * 32 + fk];
#pragma unroll
      for (int dt = 0; dt < 4; ++dt) {
        bf16x8 bv = *(const bf16x8*)&KVs[(dt * 16 + fr) * SVP + ks * 32 + fk];
        o[0][dt] = mfma16(a0, bv, o[0][dt]);
        o[1][dt] = mfma16(a1, bv, o[1][dt]);
      }
    }
  }

  // normalize + write ctx bf16 [B*S, H*DV]
#pragma unroll
  for (int qt = 0; qt < 2; ++qt)
#pragma unroll
    for (int dt = 0; dt < 4; ++dt)
#pragma unroll
      for (int r = 0; r < 4; ++r) {
        float ov = o[qt][dt][r] / lrow[qt][r];
        int srow = n * 128 + w * 32 + qt * 16 + rq + r;
        ctx[((size_t)b * 8192 + srow) * 1024 + h * 64 + dt * 16 + fr] = (bf16_t)ov;
      }
}

// ---------------- launch ----------------
extern "C" void kernel_launch(void* const* d_in, const int* in_sizes, int n_in,
                              void* d_out, int out_size, void* d_ws, size_t ws_size,
                              hipStream_t stream) {
  const float* x  = (const float*)d_in[0];
  const float* Wq = (const float*)d_in[1];
  const float* Wk = (const float*)d_in[2];
  const float* Wv = (const float*)d_in[3];
  const float* Wo = (const float*)d_in[4];
  float* out = (float*)d_out;

  char* p = (char*)d_ws;
  bf16_t* xb  = (bf16_t*)p; p += (size_t)16384 * 1024 * 2;
  bf16_t* WqT = (bf16_t*)p; p += (size_t)1024 * 1024 * 2;
  bf16_t* WkT = (bf16_t*)p; p += (size_t)1024 * 1024 * 2;
  bf16_t* WvT = (bf16_t*)p; p += (size_t)1024 * 1024 * 2;
  bf16_t* WoT = (bf16_t*)p; p += (size_t)1024 * 1024 * 2;
  bf16_t* qv  = (bf16_t*)p; p += (size_t)16384 * 1024 * 2;
  bf16_t* kv  = (bf16_t*)p; p += (size_t)16384 * 1024 * 2;
  bf16_t* vv  = (bf16_t*)p; p += (size_t)16384 * 1024 * 2;
  bf16_t* ctx = (bf16_t*)p; p += (size_t)16384 * 1024 * 2;

  cvt_bf16<<<8192, 256, 0, stream>>>(x, xb, 2097152);
  wtrans<<<dim3(32, 32, 4), dim3(32, 8), 0, stream>>>(Wq, Wk, Wv, Wo, WqT, WkT, WvT, WoT);
  gemm_bt<0><<<dim3(8, 128), 256, 0, stream>>>(xb, WqT, qv, nullptr, 16384, 1024, 1024);
  gemm_bt<0><<<dim3(8, 128), 256, 0, stream>>>(xb, WkT, kv, nullptr, 16384, 1024, 1024);
  gemm_bt<0><<<dim3(8, 128), 256, 0, stream>>>(xb, WvT, vv, nullptr, 16384, 1024, 1024);
  swa<<<dim3(64, 16, 2), 256, 0, stream>>>(qv, kv, vv, ctx);
  gemm_bt<1><<<dim3(8, 128), 256, 0, stream>>>(ctx, WoT, nullptr, out, 16384, 1024, 1024);
}

// Round 2
// 435.616 us; speedup vs baseline: 1.1600x; 1.1600x over previous
//
#include <hip/hip_runtime.h>

// B=2, S=8192, D=1024, H=16, DK=DV=64, W=Bq=128, nb=64.
// Pipeline: cvt(x->bf16) ; wtrans ; fused QKV GEMM (N=3072) ;
//           swa (no-max online softmax, mask-aware tile skip) ; out GEMM.
// ws: xb 33.5MB + WqkvT 6.3MB + WoT 2.1MB + qkv 100.7MB + ctx 33.5MB = 176.1MB

typedef __bf16 bf16_t;
typedef bf16_t bf16x8 __attribute__((ext_vector_type(8)));
typedef float f32x4 __attribute__((ext_vector_type(4)));

#define CEXP 0.18033688011112042f  // 0.125 * log2(e)

__device__ __forceinline__ f32x4 mfma16(bf16x8 a, bf16x8 b, f32x4 c) {
  return __builtin_amdgcn_mfma_f32_16x16x32_bf16(a, b, c, 0, 0, 0);
}

#define GLL16(gptr, lptr)                                                     \
  __builtin_amdgcn_global_load_lds(                                           \
      (__attribute__((address_space(1))) void*)(gptr),                        \
      (__attribute__((address_space(3))) void*)(lptr), 16, 0, 0)

// ---------------- fp32 -> bf16 convert (x) ----------------
__global__ __launch_bounds__(256) void cvt_bf16(const float* __restrict__ in,
                                                bf16_t* __restrict__ out, int n8) {
  int i = blockIdx.x * 256 + threadIdx.x;
  if (i < n8) {
    f32x4 a = *(const f32x4*)&in[(size_t)i * 8];
    f32x4 b = *(const f32x4*)&in[(size_t)i * 8 + 4];
    bf16x8 o;
#pragma unroll
    for (int j = 0; j < 4; ++j) { o[j] = (bf16_t)a[j]; o[4 + j] = (bf16_t)b[j]; }
    *(bf16x8*)&out[(size_t)i * 8] = o;
  }
}

// ---------------- weight transpose + convert: W[K][N] fp32 -> WT[N][K] bf16 ----
__global__ __launch_bounds__(256) void wtrans(const float* W0, const float* W1,
                                              const float* W2, const float* W3,
                                              bf16_t* T0, bf16_t* T1,
                                              bf16_t* T2, bf16_t* T3) {
  __shared__ float tile[32][33];
  const float* W; bf16_t* T;
  switch (blockIdx.z) {
    case 0: W = W0; T = T0; break;
    case 1: W = W1; T = T1; break;
    case 2: W = W2; T = T2; break;
    default: W = W3; T = T3; break;
  }
  int tx = threadIdx.x, ty = threadIdx.y;
  int x = blockIdx.x * 32 + tx;
  int y0 = blockIdx.y * 32;
#pragma unroll
  for (int i = ty; i < 32; i += 8) tile[i][tx] = W[(size_t)(y0 + i) * 1024 + x];
  __syncthreads();
  int xo = y0 + tx;
  int yo = blockIdx.x * 32;
#pragma unroll
  for (int i = ty; i < 32; i += 8)
    T[(size_t)(yo + i) * 1024 + xo] = (bf16_t)tile[tx][i];
}

// ---------------- GEMM: A[M,K] bf16 x Bt[N,K] bf16 -> C[M,N] ------------------
template <int OUTF>
__global__ __launch_bounds__(256) void gemm_bt(const bf16_t* __restrict__ A,
                                               const bf16_t* __restrict__ Bt,
                                               bf16_t* __restrict__ Cb,
                                               float* __restrict__ Cf,
                                               int M, int N, int K) {
  __shared__ bf16_t As[128 * 32];
  __shared__ bf16_t Bs[128 * 32];
  const int t = threadIdx.x;
  const int m0 = blockIdx.y << 7, n0 = blockIdx.x << 7;
  const int ar = t >> 2, ac = (t & 3) << 3;
  const bf16_t* Ag = A + (size_t)(m0 + ar) * K + ac;
  const bf16_t* Bg = Bt + (size_t)(n0 + ar) * K + ac;
  const size_t step64 = (size_t)64 * K;
  const int lane = t & 63;
  const int wm = ((t >> 7) & 1) << 6;
  const int wn = ((t >> 6) & 1) << 6;
  const int fr = lane & 15, fk = (lane >> 4) << 3;

  f32x4 acc[4][4] = {};
  for (int k0 = 0; k0 < K; k0 += 32) {
    GLL16(Ag + k0, &As[ar * 32 + ac]);
    GLL16(Ag + step64 + k0, &As[(ar + 64) * 32 + ac]);
    GLL16(Bg + k0, &Bs[ar * 32 + ac]);
    GLL16(Bg + step64 + k0, &Bs[(ar + 64) * 32 + ac]);
    __syncthreads();
    bf16x8 af[4], bfv[4];
#pragma unroll
    for (int i = 0; i < 4; ++i) af[i] = *(const bf16x8*)&As[(wm + i * 16 + fr) * 32 + fk];
#pragma unroll
    for (int j = 0; j < 4; ++j) bfv[j] = *(const bf16x8*)&Bs[(wn + j * 16 + fr) * 32 + fk];
#pragma unroll
    for (int i = 0; i < 4; ++i)
#pragma unroll
      for (int j = 0; j < 4; ++j) acc[i][j] = mfma16(af[i], bfv[j], acc[i][j]);
    __syncthreads();
  }
#pragma unroll
  for (int i = 0; i < 4; ++i)
#pragma unroll
    for (int j = 0; j < 4; ++j)
#pragma unroll
      for (int r = 0; r < 4; ++r) {
        int cm = m0 + wm + i * 16 + ((lane >> 4) << 2) + r;
        int cn = n0 + wn + j * 16 + fr;
        if (OUTF) Cf[(size_t)cm * N + cn] = acc[i][j][r];
        else      Cb[(size_t)cm * N + cn] = (bf16_t)acc[i][j][r];
      }
}

// ---------------- sliding-window attention ----------------
// qkv fused layout: [B*S][3072], q at col h*64, k at 1024+h*64, v at 2048+h*64.
// grid (nb=64, H=16, B=2); 256 threads = 4 waves; wave w owns q rows [w*32, w*32+32).
// No-max softmax (scores bounded ~|s|<3); mask-aware kt skipping on edge chunks.
#define SKK 72    // K tile stride (64+8)
#define SVP 136   // V^T / Ps stride (128+8)

__global__ __launch_bounds__(256, 3) void swa(const bf16_t* __restrict__ qkv,
                                              bf16_t* __restrict__ ctx) {
  __shared__ bf16_t KVs[9216];          // K tile [128][72] or V^T tile [64][136]
  __shared__ bf16_t Ps[4][32 * SVP];

  const int t = threadIdx.x;
  const int lane = t & 63;
  const int w = t >> 6;
  const int n = blockIdx.x, h = blockIdx.y, b = blockIdx.z;
  const int fr = lane & 15;
  const int fk = (lane >> 4) << 3;
  const int rq = (lane >> 4) << 2;

  // Q fragments direct from global (A-layout: m=fr, k=quad*8+j)
  bf16x8 aq[2][2];
  {
    const size_t qbase = ((size_t)b * 8192 + n * 128 + w * 32) * 3072 + h * 64;
#pragma unroll
    for (int qt = 0; qt < 2; ++qt)
#pragma unroll
      for (int ks = 0; ks < 2; ++ks)
        aq[qt][ks] = *(const bf16x8*)&qkv[qbase + (size_t)(qt * 16 + fr) * 3072 + ks * 32 + fk];
  }

  float lrow[2][4] = {};
  f32x4 o[2][4] = {};

  const int cbeg = (n == 0) ? 1 : 0;
  const int cend = (n == 63) ? 1 : 2;
  for (int ch = cbeg; ch <= cend; ++ch) {
    const int kn = n + ch - 1;
    const size_t krow0 = (size_t)b * 8192 + (size_t)kn * 128;
    __syncthreads();  // prev PV reads of KVs done
    // stage K chunk [128 keys][64 dk] -> KVs (padded stride 72)
#pragma unroll
    for (int it = 0; it < 4; ++it) {
      int c = it * 256 + t;
      int row = c >> 3, c8 = (c & 7) << 3;
      bf16x8 v = *(const bf16x8*)&qkv[(krow0 + row) * 3072 + 1024 + h * 64 + c8];
      *(bf16x8*)&KVs[row * SKK + c8] = v;
    }
    __syncthreads();

    // per-(qt) valid kt ranges on edge chunks (triangular band)
    const int lo0 = (ch == 0) ? 2 * w     : 0;
    const int hi0 = (ch == 2) ? 2 * w     : 7;
    const int lo1 = (ch == 0) ? 2 * w + 1 : 0;
    const int hi1 = (ch == 2) ? 2 * w + 1 : 7;

    // S = Q K^T over valid tiles
    f32x4 s[2][8];
#pragma unroll
    for (int kt = 0; kt < 8; ++kt) {
      const bool need0 = (kt >= lo0) & (kt <= hi0);
      const bool need1 = (kt >= lo1) & (kt <= hi1);
      if (need0 | need1) {
        bf16x8 b0 = *(const bf16x8*)&KVs[(kt * 16 + fr) * SKK + fk];
        bf16x8 b1 = *(const bf16x8*)&KVs[(kt * 16 + fr) * SKK + 32 + fk];
        if (need0) s[0][kt] = mfma16(aq[0][1], b1, mfma16(aq[0][0], b0, (f32x4){0.f, 0.f, 0.f, 0.f}));
        if (need1) s[1][kt] = mfma16(aq[1][1], b1, mfma16(aq[1][0], b0, (f32x4){0.f, 0.f, 0.f, 0.f}));
      }
    }

    // exp (no max-subtraction), diagonal-tile masking, P store, partial row sums
#pragma unroll
    for (int qt = 0; qt < 2; ++qt) {
      const int lo = qt ? lo1 : lo0;
      const int hi = qt ? hi1 : hi0;
#pragma unroll
      for (int kt = 0; kt < 8; ++kt) {
        if (kt < lo || kt > hi) continue;
        const bool dL = (ch == 0) && (kt == lo);
        const bool dR = (ch == 2) && (kt == hi);
#pragma unroll
        for (int r = 0; r < 4; ++r) {
          float p = exp2f(s[qt][kt][r] * CEXP);
          if (dL) p = (fr >= rq + r) ? p : 0.f;
          if (dR) p = (fr <= rq + r) ? p : 0.f;
          lrow[qt][r] += p;
          Ps[w][(qt * 16 + rq + r) * SVP + kt * 16 + fr] = (bf16_t)p;
        }
      }
    }
    // zero-fill the one read-but-unwritten Ps tile on edge chunks
    if (ch == 0) {
#pragma unroll
      for (int r = 0; r < 4; ++r)
        Ps[w][(16 + rq + r) * SVP + 2 * w * 16 + fr] = (bf16_t)0.f;
    } else if (ch == 2) {
#pragma unroll
      for (int r = 0; r < 4; ++r)
        Ps[w][(rq + r) * SVP + (2 * w + 1) * 16 + fr] = (bf16_t)0.f;
    }

    __syncthreads();  // all waves done reading K from KVs
    // stage V^T [64 dv][128 keys] -> KVs (stride 136)
#pragma unroll
    for (int it = 0; it < 4; ++it) {
      int c = it * 256 + t;
      int key = c & 127, d8 = (c >> 7) << 3;
      bf16x8 vv = *(const bf16x8*)&qkv[(krow0 + key) * 3072 + 2048 + h * 64 + d8];
#pragma unroll
      for (int j = 0; j < 8; ++j) KVs[(d8 + j) * SVP + key] = vv[j];
    }
    __syncthreads();

    // O += P V over valid key 32-blocks
    const int pl = (ch == 0) ? w : 0;
    const int ph = (ch == 2) ? w : 3;
#pragma unroll
    for (int ks = 0; ks < 4; ++ks) {
      if (ks < pl || ks > ph) continue;
      bf16x8 a0 = *(const bf16x8*)&Ps[w][(fr) * SVP + ks * 32 + fk];
      bf16x8 a1 = *(const bf16x8*)&Ps[w][(16 + fr) * SVP + ks * 32 + fk];
#pragma unroll
      for (int dt = 0; dt < 4; ++dt) {
        bf16x8 bv = *(const bf16x8*)&KVs[(dt * 16 + fr) * SVP + ks * 32 + fk];
        o[0][dt] = mfma16(a0, bv, o[0][dt]);
        o[1][dt] = mfma16(a1, bv, o[1][dt]);
      }
    }
  }

  // single cross-lane row-sum reduction (over the 16 fr lanes in each quad-group)
#pragma unroll
  for (int qt = 0; qt < 2; ++qt)
#pragma unroll
    for (int r = 0; r < 4; ++r)
#pragma unroll
      for (int d = 1; d < 16; d <<= 1)
        lrow[qt][r] += __shfl_xor(lrow[qt][r], d, 64);

  // normalize + write ctx bf16 [B*S][1024]
#pragma unroll
  for (int qt = 0; qt < 2; ++qt)
#pragma unroll
    for (int dt = 0; dt < 4; ++dt)
#pragma unroll
      for (int r = 0; r < 4; ++r) {
        float ov = o[qt][dt][r] / lrow[qt][r];
        int srow = n * 128 + w * 32 + qt * 16 + rq + r;
        ctx[((size_t)b * 8192 + srow) * 1024 + h * 64 + dt * 16 + fr] = (bf16_t)ov;
      }
}

// ---------------- launch ----------------
extern "C" void kernel_launch(void* const* d_in, const int* in_sizes, int n_in,
                              void* d_out, int out_size, void* d_ws, size_t ws_size,
                              hipStream_t stream) {
  const float* x  = (const float*)d_in[0];
  const float* Wq = (const float*)d_in[1];
  const float* Wk = (const float*)d_in[2];
  const float* Wv = (const float*)d_in[3];
  const float* Wo = (const float*)d_in[4];
  float* out = (float*)d_out;

  char* p = (char*)d_ws;
  bf16_t* xb    = (bf16_t*)p; p += (size_t)16384 * 1024 * 2;
  bf16_t* WqkvT = (bf16_t*)p; p += (size_t)3 * 1024 * 1024 * 2;
  bf16_t* WoT   = (bf16_t*)p; p += (size_t)1024 * 1024 * 2;
  bf16_t* qkv   = (bf16_t*)p; p += (size_t)16384 * 3072 * 2;
  bf16_t* ctx   = (bf16_t*)p; p += (size_t)16384 * 1024 * 2;

  cvt_bf16<<<8192, 256, 0, stream>>>(x, xb, 2097152);
  wtrans<<<dim3(32, 32, 4), dim3(32, 8), 0, stream>>>(
      Wq, Wk, Wv, Wo, WqkvT, WqkvT + (size_t)1024 * 1024, WqkvT + (size_t)2 * 1024 * 1024, WoT);
  gemm_bt<0><<<dim3(24, 128), 256, 0, stream>>>(xb, WqkvT, qkv, nullptr, 16384, 3072, 1024);
  swa<<<dim3(64, 16, 2), 256, 0, stream>>>(qkv, ctx);
  gemm_bt<1><<<dim3(8, 128), 256, 0, stream>>>(ctx, WoT, nullptr, out, 16384, 1024, 1024);
}

// Round 3
// 417.415 us; speedup vs baseline: 1.2106x; 1.0436x over previous
//
#include <hip/hip_runtime.h>

// B=2, S=8192, D=1024, H=16, DK=DV=64, W=Bq=128, nb=64.
// Pipeline: cvt(x->bf16) ; wtrans ; fused QKV GEMM (N=3072) ; vtrans (V^T swizzled) ;
//           swa (S^T-form MFMA, no-max softmax, 2 barriers/chunk, VGPR prefetch) ; out GEMM.
// ws: xb 33.5MB (reused as vT) + WqkvT 6.3MB + WoT 2.1MB + qkv 100.7MB + ctx 33.5MB

typedef __bf16 bf16_t;
typedef bf16_t bf16x8 __attribute__((ext_vector_type(8)));
typedef bf16_t bf16x4 __attribute__((ext_vector_type(4)));
typedef float f32x4 __attribute__((ext_vector_type(4)));

#define CEXP 0.18033688011112042f  // 0.125 * log2(e)

__device__ __forceinline__ f32x4 mfma16(bf16x8 a, bf16x8 b, f32x4 c) {
  return __builtin_amdgcn_mfma_f32_16x16x32_bf16(a, b, c, 0, 0, 0);
}

#define GLL16(gptr, lptr)                                                     \
  __builtin_amdgcn_global_load_lds(                                           \
      (__attribute__((address_space(1))) void*)(gptr),                        \
      (__attribute__((address_space(3))) void*)(lptr), 16, 0, 0)

// ---------------- fp32 -> bf16 convert (x) ----------------
__global__ __launch_bounds__(256) void cvt_bf16(const float* __restrict__ in,
                                                bf16_t* __restrict__ out, int n8) {
  int i = blockIdx.x * 256 + threadIdx.x;
  if (i < n8) {
    f32x4 a = *(const f32x4*)&in[(size_t)i * 8];
    f32x4 b = *(const f32x4*)&in[(size_t)i * 8 + 4];
    bf16x8 o;
#pragma unroll
    for (int j = 0; j < 4; ++j) { o[j] = (bf16_t)a[j]; o[4 + j] = (bf16_t)b[j]; }
    *(bf16x8*)&out[(size_t)i * 8] = o;
  }
}

// ---------------- weight transpose + convert: W[K][N] fp32 -> WT[N][K] bf16 ----
__global__ __launch_bounds__(256) void wtrans(const float* W0, const float* W1,
                                              const float* W2, const float* W3,
                                              bf16_t* T0, bf16_t* T1,
                                              bf16_t* T2, bf16_t* T3) {
  __shared__ float tile[32][33];
  const float* W; bf16_t* T;
  switch (blockIdx.z) {
    case 0: W = W0; T = T0; break;
    case 1: W = W1; T = T1; break;
    case 2: W = W2; T = T2; break;
    default: W = W3; T = T3; break;
  }
  int tx = threadIdx.x, ty = threadIdx.y;
  int x = blockIdx.x * 32 + tx;
  int y0 = blockIdx.y * 32;
#pragma unroll
  for (int i = ty; i < 32; i += 8) tile[i][tx] = W[(size_t)(y0 + i) * 1024 + x];
  __syncthreads();
  int xo = y0 + tx;
  int yo = blockIdx.x * 32;
#pragma unroll
  for (int i = ty; i < 32; i += 8)
    T[(size_t)(yo + i) * 1024 + xo] = (bf16_t)tile[tx][i];
}

// ---------------- GEMM: A[M,K] bf16 x Bt[N,K] bf16 -> C[M,N] ------------------
template <int OUTF>
__global__ __launch_bounds__(256) void gemm_bt(const bf16_t* __restrict__ A,
                                               const bf16_t* __restrict__ Bt,
                                               bf16_t* __restrict__ Cb,
                                               float* __restrict__ Cf,
                                               int M, int N, int K) {
  __shared__ bf16_t As[128 * 32];
  __shared__ bf16_t Bs[128 * 32];
  const int t = threadIdx.x;
  const int m0 = blockIdx.y << 7, n0 = blockIdx.x << 7;
  const int ar = t >> 2, ac = (t & 3) << 3;
  const bf16_t* Ag = A + (size_t)(m0 + ar) * K + ac;
  const bf16_t* Bg = Bt + (size_t)(n0 + ar) * K + ac;
  const size_t step64 = (size_t)64 * K;
  const int lane = t & 63;
  const int wm = ((t >> 7) & 1) << 6;
  const int wn = ((t >> 6) & 1) << 6;
  const int fr = lane & 15, fk = (lane >> 4) << 3;

  f32x4 acc[4][4] = {};
  for (int k0 = 0; k0 < K; k0 += 32) {
    GLL16(Ag + k0, &As[ar * 32 + ac]);
    GLL16(Ag + step64 + k0, &As[(ar + 64) * 32 + ac]);
    GLL16(Bg + k0, &Bs[ar * 32 + ac]);
    GLL16(Bg + step64 + k0, &Bs[(ar + 64) * 32 + ac]);
    __syncthreads();
    bf16x8 af[4], bfv[4];
#pragma unroll
    for (int i = 0; i < 4; ++i) af[i] = *(const bf16x8*)&As[(wm + i * 16 + fr) * 32 + fk];
#pragma unroll
    for (int j = 0; j < 4; ++j) bfv[j] = *(const bf16x8*)&Bs[(wn + j * 16 + fr) * 32 + fk];
#pragma unroll
    for (int i = 0; i < 4; ++i)
#pragma unroll
      for (int j = 0; j < 4; ++j) acc[i][j] = mfma16(af[i], bfv[j], acc[i][j]);
    __syncthreads();
  }
#pragma unroll
  for (int i = 0; i < 4; ++i)
#pragma unroll
    for (int j = 0; j < 4; ++j)
#pragma unroll
      for (int r = 0; r < 4; ++r) {
        int cm = m0 + wm + i * 16 + ((lane >> 4) << 2) + r;
        int cn = n0 + wn + j * 16 + fr;
        if (OUTF) Cf[(size_t)cm * N + cn] = acc[i][j][r];
        else      Cb[(size_t)cm * N + cn] = (bf16_t)acc[i][j][r];
      }
}

// ---------------- V transpose + swizzle -----------------
// qkv v-part [b][s][2048 + h*64 + dv] -> vT[(b*16+h)*64 + dv][8192 keys],
// within each 128-key segment the 16B chunks are stored at (chunk ^ (dv&15)).
__global__ __launch_bounds__(256) void vtrans(const bf16_t* __restrict__ qkv,
                                              bf16_t* __restrict__ vT) {
  __shared__ bf16_t tile[128][72];   // [key][dv], pad to 72
  const int seg = blockIdx.x, h = blockIdx.y, b = blockIdx.z;
  const int t = threadIdx.x;
#pragma unroll
  for (int it = 0; it < 4; ++it) {
    int c = it * 256 + t;            // 1024 chunks of 8 elements
    int row = c >> 3, c8 = (c & 7) << 3;
    bf16x8 v = *(const bf16x8*)&qkv[((size_t)(b * 8192 + seg * 128 + row)) * 3072 + 2048 + h * 64 + c8];
    *(bf16x8*)&tile[row][c8] = v;
  }
  __syncthreads();
#pragma unroll
  for (int it = 0; it < 4; ++it) {
    int c = it * 256 + t;
    int dv = c >> 4, ck = c & 15;    // out chunk = 8 keys of one dv row
    bf16x8 o;
#pragma unroll
    for (int j = 0; j < 8; ++j) o[j] = tile[ck * 8 + j][dv];
    size_t rowg = (size_t)(b * 16 + h) * 64 + dv;
    *(bf16x8*)&vT[rowg * 8192 + seg * 128 + ((ck ^ (dv & 15)) << 3)] = o;
  }
}

// ---------------- sliding-window attention ----------------
// S^T = K Q^T form: MFMA D[key][q]; P^T lands with q on lane&15 and 4 consecutive
// keys per accumulator register -> b64 stores into per-wave PsT, then direct
// A-frag reads for P·V. 2 barriers per chunk; K/V prefetched into VGPRs.
#define SKK 72    // K tile stride (64+8)
#define PST 136   // PsT stride (128+8)

__global__ __launch_bounds__(256, 3) void swa(const bf16_t* __restrict__ qkv,
                                              const bf16_t* __restrict__ vT,
                                              bf16_t* __restrict__ ctx) {
  __shared__ bf16_t Ks[128 * SKK];       // 18.4 KB [key][dk]
  __shared__ bf16_t Vs[64 * 128];        // 16 KB   [dv][key] swizzled image
  __shared__ bf16_t PsT[4][16 * PST];    // 17.4 KB per-wave P^T [q16][key]

  const int t = threadIdx.x, lane = t & 63, w = t >> 6;
  const int n = blockIdx.x, h = blockIdx.y, b = blockIdx.z;
  const int fr = lane & 15, quad = lane >> 4, fk = quad << 3;

  // Q fragments (B-operand: n=q=fr, k=dk=quad*8+j)
  bf16x8 aq[2][2];
  {
    const size_t qbase = ((size_t)b * 8192 + n * 128 + w * 32) * 3072 + h * 64;
#pragma unroll
    for (int qt = 0; qt < 2; ++qt)
#pragma unroll
      for (int ks = 0; ks < 2; ++ks)
        aq[qt][ks] = *(const bf16x8*)&qkv[qbase + (size_t)(qt * 16 + fr) * 3072 + ks * 32 + fk];
  }

  const size_t kcol = 1024 + h * 64;
  const size_t vbase = (size_t)(b * 16 + h) * 64 * 8192;

  bf16x8 kr[4], vr[4];
  auto loadKV = [&](int kn) {
    const size_t krow0 = (size_t)b * 8192 + (size_t)kn * 128;
#pragma unroll
    for (int it = 0; it < 4; ++it) {
      int c = it * 256 + t;
      kr[it] = *(const bf16x8*)&qkv[(krow0 + (c >> 3)) * 3072 + kcol + ((c & 7) << 3)];
      vr[it] = *(const bf16x8*)&vT[vbase + (size_t)(c >> 4) * 8192 + kn * 128 + ((c & 15) << 3)];
    }
  };

  const int cbeg = (n == 0) ? 1 : 0;
  const int cend = (n == 63) ? 1 : 2;
  loadKV(n + cbeg - 1);

  float lrow[2] = {0.f, 0.f};
  f32x4 o[2][4] = {};   // C-layout O[q][dv]: col dv = fr, row q = quad*4+r (+16*qt)

  for (int ch = cbeg; ch <= cend; ++ch) {
    __syncthreads();   // waves done reading Ks/Vs of prev chunk; drains prefetch vmcnt
#pragma unroll
    for (int it = 0; it < 4; ++it) {
      int c = it * 256 + t;
      *(bf16x8*)&Ks[(c >> 3) * SKK + ((c & 7) << 3)] = kr[it];
      *(bf16x8*)&Vs[c << 3] = vr[it];
    }
    __syncthreads();   // cheap: lgkm only, VM queue empty
    if (ch < cend) loadKV(n + ch);   // next chunk's loads fly during compute

#pragma unroll
    for (int qt = 0; qt < 2; ++qt) {
      const int lo = (ch == 0) ? 2 * w + qt : 0;
      const int hi = (ch == 2) ? 2 * w + qt : 7;

      // S^T tiles: D[key][q], A = K (m=key=fr, k=dk), B = Q
      f32x4 st[8];
#pragma unroll
      for (int kt = 0; kt < 8; ++kt) {
        if (kt < lo || kt > hi) continue;
        bf16x8 k0 = *(const bf16x8*)&Ks[(kt * 16 + fr) * SKK + fk];
        bf16x8 k1 = *(const bf16x8*)&Ks[(kt * 16 + fr) * SKK + 32 + fk];
        st[kt] = mfma16(k1, aq[qt][1], mfma16(k0, aq[qt][0], (f32x4){0.f, 0.f, 0.f, 0.f}));
      }

      // exp + diagonal mask + P^T write (b64: 4 consecutive keys per lane)
#pragma unroll
      for (int kt = 0; kt < 8; ++kt) {
        if (kt < lo || kt > hi) continue;
        const bool dL = (ch == 0) && (kt == lo);
        const bool dR = (ch == 2) && (kt == hi);
        bf16x4 pk;
#pragma unroll
        for (int r = 0; r < 4; ++r) {
          float p = exp2f(st[kt][r] * CEXP);
          int kl = quad * 4 + r;     // key within tile; q within tile = fr
          if (dL) p = (kl >= fr) ? p : 0.f;
          if (dR) p = (kl <= fr) ? p : 0.f;
          lrow[qt] += p;
          pk[r] = (bf16_t)p;
        }
        *(bf16x4*)&PsT[w][fr * PST + kt * 16 + quad * 4] = pk;
      }
      // zero-fill the single read-but-unwritten tile on edge chunks
      if ((ch == 0) && (lo & 1)) {
        bf16x4 zz; zz[0] = zz[1] = zz[2] = zz[3] = (bf16_t)0.f;
        *(bf16x4*)&PsT[w][fr * PST + (lo - 1) * 16 + quad * 4] = zz;
      }
      if ((ch == 2) && !(hi & 1)) {
        bf16x4 zz; zz[0] = zz[1] = zz[2] = zz[3] = (bf16_t)0.f;
        *(bf16x4*)&PsT[w][fr * PST + (hi + 1) * 16 + quad * 4] = zz;
      }

      // O += P V  (A = P [m=q=fr, k=key], B = V^T swizzled [n=dv=fr, k=key])
      const int pl = lo >> 1, ph = hi >> 1;
#pragma unroll
      for (int ks = 0; ks < 4; ++ks) {
        if (ks < pl || ks > ph) continue;
        bf16x8 pa = *(const bf16x8*)&PsT[w][fr * PST + ks * 32 + fk];
#pragma unroll
        for (int dt = 0; dt < 4; ++dt) {
          bf16x8 bv = *(const bf16x8*)&Vs[(dt * 16 + fr) * 128 + ((((ks << 2) + quad) ^ fr) << 3)];
          o[qt][dt] = mfma16(pa, bv, o[qt][dt]);
        }
      }
    }
  }

  // finish row sums: reduce over quads, then redistribute to O's row indexing
#pragma unroll
  for (int qt = 0; qt < 2; ++qt) {
    lrow[qt] += __shfl_xor(lrow[qt], 16, 64);
    lrow[qt] += __shfl_xor(lrow[qt], 32, 64);
  }
  float ln[2][4];
#pragma unroll
  for (int qt = 0; qt < 2; ++qt)
#pragma unroll
    for (int r = 0; r < 4; ++r)
      ln[qt][r] = __shfl(lrow[qt], quad * 4 + r, 64);

#pragma unroll
  for (int qt = 0; qt < 2; ++qt)
#pragma unroll
    for (int dt = 0; dt < 4; ++dt)
#pragma unroll
      for (int r = 0; r < 4; ++r) {
        float ov = o[qt][dt][r] / ln[qt][r];
        int srow = n * 128 + w * 32 + qt * 16 + quad * 4 + r;
        ctx[((size_t)b * 8192 + srow) * 1024 + h * 64 + dt * 16 + fr] = (bf16_t)ov;
      }
}

// ---------------- launch ----------------
extern "C" void kernel_launch(void* const* d_in, const int* in_sizes, int n_in,
                              void* d_out, int out_size, void* d_ws, size_t ws_size,
                              hipStream_t stream) {
  const float* x  = (const float*)d_in[0];
  const float* Wq = (const float*)d_in[1];
  const float* Wk = (const float*)d_in[2];
  const float* Wv = (const float*)d_in[3];
  const float* Wo = (const float*)d_in[4];
  float* out = (float*)d_out;

  char* p = (char*)d_ws;
  bf16_t* xb    = (bf16_t*)p; p += (size_t)16384 * 1024 * 2;   // reused as vT after QKV GEMM
  bf16_t* WqkvT = (bf16_t*)p; p += (size_t)3 * 1024 * 1024 * 2;
  bf16_t* WoT   = (bf16_t*)p; p += (size_t)1024 * 1024 * 2;
  bf16_t* qkv   = (bf16_t*)p; p += (size_t)16384 * 3072 * 2;
  bf16_t* ctx   = (bf16_t*)p; p += (size_t)16384 * 1024 * 2;
  bf16_t* vT    = xb;  // xb is dead after the QKV GEMM

  cvt_bf16<<<8192, 256, 0, stream>>>(x, xb, 2097152);
  wtrans<<<dim3(32, 32, 4), dim3(32, 8), 0, stream>>>(
      Wq, Wk, Wv, Wo, WqkvT, WqkvT + (size_t)1024 * 1024, WqkvT + (size_t)2 * 1024 * 1024, WoT);
  gemm_bt<0><<<dim3(24, 128), 256, 0, stream>>>(xb, WqkvT, qkv, nullptr, 16384, 3072, 1024);
  vtrans<<<dim3(64, 16, 2), 256, 0, stream>>>(qkv, vT);
  swa<<<dim3(64, 16, 2), 256, 0, stream>>>(qkv, vT, ctx);
  gemm_bt<1><<<dim3(8, 128), 256, 0, stream>>>(ctx, WoT, nullptr, out, 16384, 1024, 1024);
}

// Round 4
// 376.365 us; speedup vs baseline: 1.3426x; 1.1091x over previous
//
#include <hip/hip_runtime.h>

// B=2, S=8192, D=1024, H=16, DK=DV=64, W=Bq=128, nb=64.
// Pipeline: prep(cvt x->bf16 + 4x weight transpose) ;
//           gemm_qkv (fused N=3072, epilogue scatters q/k per-head + V transposed tiles) ;
//           swa (S^T-form MFMA, no-max softmax, 2 barriers/chunk, VGPR prefetch) ;
//           gemm_bt (out proj, fp32 out).
// ws: xb 33.5 + WqkvT 6.3 + WoT 2.1 + qh 33.5 + kh 33.5 + vT2 33.5 + ctx 33.5 = 176MB

typedef __bf16 bf16_t;
typedef bf16_t bf16x8 __attribute__((ext_vector_type(8)));
typedef bf16_t bf16x4 __attribute__((ext_vector_type(4)));
typedef float f32x4 __attribute__((ext_vector_type(4)));

#define CEXP 0.18033688011112042f  // 0.125 * log2(e)

__device__ __forceinline__ f32x4 mfma16(bf16x8 a, bf16x8 b, f32x4 c) {
  return __builtin_amdgcn_mfma_f32_16x16x32_bf16(a, b, c, 0, 0, 0);
}

#define GLL16(gptr, lptr)                                                     \
  __builtin_amdgcn_global_load_lds(                                           \
      (__attribute__((address_space(1))) void*)(gptr),                        \
      (__attribute__((address_space(3))) void*)(lptr), 16, 0, 0)

// ---------------- prep: x fp32->bf16 (blocks 0..8191) + weight transpose (8192..12287)
__global__ __launch_bounds__(256) void prep(const float* __restrict__ x,
                                            const float* __restrict__ W0,
                                            const float* __restrict__ W1,
                                            const float* __restrict__ W2,
                                            const float* __restrict__ W3,
                                            bf16_t* __restrict__ xb,
                                            bf16_t* T0, bf16_t* T1,
                                            bf16_t* T2, bf16_t* T3) {
  __shared__ float tile[32][33];
  const int t = threadIdx.x;
  if (blockIdx.x < 8192) {
    int i = blockIdx.x * 256 + t;
    f32x4 a = *(const f32x4*)&x[(size_t)i * 8];
    f32x4 b = *(const f32x4*)&x[(size_t)i * 8 + 4];
    bf16x8 o;
#pragma unroll
    for (int j = 0; j < 4; ++j) { o[j] = (bf16_t)a[j]; o[4 + j] = (bf16_t)b[j]; }
    *(bf16x8*)&xb[(size_t)i * 8] = o;
    return;
  }
  int wb = blockIdx.x - 8192;
  int z = wb >> 10, rem = wb & 1023;
  int bx = rem & 31, by = rem >> 5;
  const float* W; bf16_t* T;
  switch (z) {
    case 0: W = W0; T = T0; break;
    case 1: W = W1; T = T1; break;
    case 2: W = W2; T = T2; break;
    default: W = W3; T = T3; break;
  }
  int tx = t & 31, ty = t >> 5;
  int xc = bx * 32 + tx;
  int y0 = by * 32;
#pragma unroll
  for (int i = ty; i < 32; i += 8) tile[i][tx] = W[(size_t)(y0 + i) * 1024 + xc];
  __syncthreads();
  int xo = y0 + tx;
  int yo = bx * 32;
#pragma unroll
  for (int i = ty; i < 32; i += 8)
    T[(size_t)(yo + i) * 1024 + xo] = (bf16_t)tile[tx][i];
}

// ---------------- fused QKV GEMM: xb[16384,1024] x WqkvT[3072,1024]^T -------------
// Epilogue: cols 0..1023 -> qh[b,h,s,64]; 1024..2047 -> kh[b,h,s,64];
//           2048..3071 -> vT2 tiles [bh][sblk=s/16][dv][16s] (b64 coalesced stores).
__global__ __launch_bounds__(256) void gemm_qkv(const bf16_t* __restrict__ A,
                                                const bf16_t* __restrict__ Bt,
                                                bf16_t* __restrict__ qh,
                                                bf16_t* __restrict__ kh,
                                                bf16_t* __restrict__ vT2) {
  __shared__ bf16_t As[128 * 32];
  __shared__ bf16_t Bs[128 * 32];
  const int t = threadIdx.x;
  const int K = 1024;
  const int m0 = blockIdx.y << 7, n0 = blockIdx.x << 7;
  const int ar = t >> 2, ac = (t & 3) << 3;
  const bf16_t* Ag = A + (size_t)(m0 + ar) * K + ac;
  const bf16_t* Bg = Bt + (size_t)(n0 + ar) * K + ac;
  const size_t step64 = (size_t)64 * K;
  const int lane = t & 63;
  const int wm = ((t >> 7) & 1) << 6;
  const int wn = ((t >> 6) & 1) << 6;
  const int fr = lane & 15, quad = lane >> 4, fk = quad << 3;

  f32x4 acc[4][4] = {};
  for (int k0 = 0; k0 < K; k0 += 32) {
    GLL16(Ag + k0, &As[ar * 32 + ac]);
    GLL16(Ag + step64 + k0, &As[(ar + 64) * 32 + ac]);
    GLL16(Bg + k0, &Bs[ar * 32 + ac]);
    GLL16(Bg + step64 + k0, &Bs[(ar + 64) * 32 + ac]);
    __syncthreads();
    bf16x8 af[4], bfv[4];
#pragma unroll
    for (int i = 0; i < 4; ++i) af[i] = *(const bf16x8*)&As[(wm + i * 16 + fr) * 32 + fk];
#pragma unroll
    for (int j = 0; j < 4; ++j) bfv[j] = *(const bf16x8*)&Bs[(wn + j * 16 + fr) * 32 + fk];
#pragma unroll
    for (int i = 0; i < 4; ++i)
#pragma unroll
      for (int j = 0; j < 4; ++j) acc[i][j] = mfma16(af[i], bfv[j], acc[i][j]);
    __syncthreads();
  }

  const int colbase = n0 + wn;           // multiple of 64 -> single head per wave-half
  if (colbase < 2048) {
    bf16_t* dst = (colbase < 1024) ? qh : kh;
    const int cb = colbase & 1023;
#pragma unroll
    for (int i = 0; i < 4; ++i)
#pragma unroll
      for (int j = 0; j < 4; ++j) {
        int col = cb + j * 16 + fr;
        int h = col >> 6, dk = col & 63;
#pragma unroll
        for (int r = 0; r < 4; ++r) {
          int cm = m0 + wm + i * 16 + quad * 4 + r;
          int b = cm >> 13, s = cm & 8191;
          dst[((((size_t)(b * 16 + h) << 13) | s) << 6) | dk] = (bf16_t)acc[i][j][r];
        }
      }
  } else {
    const int cb = colbase - 2048;
#pragma unroll
    for (int i = 0; i < 4; ++i) {
      int s0 = m0 + wm + i * 16;
      int b = s0 >> 13, sblk = (s0 & 8191) >> 4;
#pragma unroll
      for (int j = 0; j < 4; ++j) {
        int col = cb + j * 16;
        int h = col >> 6, dv = (col & 63) + fr;
        bf16x4 pk;
#pragma unroll
        for (int r = 0; r < 4; ++r) pk[r] = (bf16_t)acc[i][j][r];
        *(bf16x4*)&vT2[((size_t)(b * 16 + h) * 512 + sblk) * 1024 + dv * 16 + quad * 4] = pk;
      }
    }
  }
}

// ---------------- GEMM: A[M,K] bf16 x Bt[N,K] bf16 -> C fp32 (out proj) ----------
__global__ __launch_bounds__(256) void gemm_bt(const bf16_t* __restrict__ A,
                                               const bf16_t* __restrict__ Bt,
                                               float* __restrict__ Cf,
                                               int M, int N, int K) {
  __shared__ bf16_t As[128 * 32];
  __shared__ bf16_t Bs[128 * 32];
  const int t = threadIdx.x;
  const int m0 = blockIdx.y << 7, n0 = blockIdx.x << 7;
  const int ar = t >> 2, ac = (t & 3) << 3;
  const bf16_t* Ag = A + (size_t)(m0 + ar) * K + ac;
  const bf16_t* Bg = Bt + (size_t)(n0 + ar) * K + ac;
  const size_t step64 = (size_t)64 * K;
  const int lane = t & 63;
  const int wm = ((t >> 7) & 1) << 6;
  const int wn = ((t >> 6) & 1) << 6;
  const int fr = lane & 15, fk = (lane >> 4) << 3;

  f32x4 acc[4][4] = {};
  for (int k0 = 0; k0 < K; k0 += 32) {
    GLL16(Ag + k0, &As[ar * 32 + ac]);
    GLL16(Ag + step64 + k0, &As[(ar + 64) * 32 + ac]);
    GLL16(Bg + k0, &Bs[ar * 32 + ac]);
    GLL16(Bg + step64 + k0, &Bs[(ar + 64) * 32 + ac]);
    __syncthreads();
    bf16x8 af[4], bfv[4];
#pragma unroll
    for (int i = 0; i < 4; ++i) af[i] = *(const bf16x8*)&As[(wm + i * 16 + fr) * 32 + fk];
#pragma unroll
    for (int j = 0; j < 4; ++j) bfv[j] = *(const bf16x8*)&Bs[(wn + j * 16 + fr) * 32 + fk];
#pragma unroll
    for (int i = 0; i < 4; ++i)
#pragma unroll
      for (int j = 0; j < 4; ++j) acc[i][j] = mfma16(af[i], bfv[j], acc[i][j]);
    __syncthreads();
  }
#pragma unroll
  for (int i = 0; i < 4; ++i)
#pragma unroll
    for (int j = 0; j < 4; ++j)
#pragma unroll
      for (int r = 0; r < 4; ++r) {
        int cm = m0 + wm + i * 16 + ((lane >> 4) << 2) + r;
        int cn = n0 + wn + j * 16 + fr;
        Cf[(size_t)cm * N + cn] = acc[i][j][r];
      }
}

// ---------------- sliding-window attention ----------------
// qh/kh: [b*16+h][8192][64]; vT2: [b*16+h][512 sblk][64 dv][16 s].
// S^T = K Q^T form; P^T b64 stores; 2 barriers/chunk; K/V prefetched into VGPRs.
#define SKK 72    // K tile stride (64+8)
#define SVS 136   // Vs stride (128+8)
#define PST 136   // PsT stride (128+8)

__global__ __launch_bounds__(256, 3) void swa(const bf16_t* __restrict__ qh,
                                              const bf16_t* __restrict__ kh,
                                              const bf16_t* __restrict__ vT2,
                                              bf16_t* __restrict__ ctx) {
  __shared__ bf16_t Ks[128 * SKK];       // 18.4 KB [key][dk]
  __shared__ bf16_t Vs[64 * SVS];        // 17.4 KB [dv][key]
  __shared__ bf16_t PsT[4][16 * PST];    // 17.4 KB per-wave P^T [q16][key]

  const int t = threadIdx.x, lane = t & 63, w = t >> 6;
  const int n = blockIdx.x, h = blockIdx.y, b = blockIdx.z;
  const int fr = lane & 15, quad = lane >> 4, fk = quad << 3;
  const size_t bh = (size_t)(b * 16 + h);

  // Q fragments (B-operand: n=q=fr, k=dk=quad*8+j)
  bf16x8 aq[2][2];
  {
    const size_t qbase = (bh * 8192 + n * 128 + w * 32) * 64;
#pragma unroll
    for (int qt = 0; qt < 2; ++qt)
#pragma unroll
      for (int ks = 0; ks < 2; ++ks)
        aq[qt][ks] = *(const bf16x8*)&qh[qbase + (size_t)(qt * 16 + fr) * 64 + ks * 32 + fk];
  }

  bf16x8 kr[4], vr[4];
  auto loadKV = [&](int kn) {
#pragma unroll
    for (int it = 0; it < 4; ++it) {
      int c = it * 256 + t;
      kr[it] = *(const bf16x8*)&kh[(bh * 8192 + kn * 128 + (c >> 3)) * 64 + ((c & 7) << 3)];
      int sb = c >> 7, dv = (c & 127) >> 1, sh = c & 1;
      vr[it] = *(const bf16x8*)&vT2[(bh * 512 + kn * 8 + sb) * 1024 + dv * 16 + sh * 8];
    }
  };

  const int cbeg = (n == 0) ? 1 : 0;
  const int cend = (n == 63) ? 1 : 2;
  loadKV(n + cbeg - 1);

  float lrow[2] = {0.f, 0.f};
  f32x4 o[2][4] = {};   // C-layout O[q][dv]: col dv = fr, row q = quad*4+r (+16*qt)

  for (int ch = cbeg; ch <= cend; ++ch) {
    __syncthreads();   // waves done reading Ks/Vs of prev chunk; drains prefetch vmcnt
#pragma unroll
    for (int it = 0; it < 4; ++it) {
      int c = it * 256 + t;
      *(bf16x8*)&Ks[(c >> 3) * SKK + ((c & 7) << 3)] = kr[it];
      int sb = c >> 7, dv = (c & 127) >> 1, sh = c & 1;
      *(bf16x8*)&Vs[dv * SVS + sb * 16 + sh * 8] = vr[it];
    }
    __syncthreads();   // cheap: lgkm only, VM queue empty
    if (ch < cend) loadKV(n + ch);   // next chunk's loads fly during compute

#pragma unroll
    for (int qt = 0; qt < 2; ++qt) {
      const int lo = (ch == 0) ? 2 * w + qt : 0;
      const int hi = (ch == 2) ? 2 * w + qt : 7;

      // S^T tiles: D[key][q], A = K (m=key=fr, k=dk), B = Q
      f32x4 st[8];
#pragma unroll
      for (int kt = 0; kt < 8; ++kt) {
        if (kt < lo || kt > hi) continue;
        bf16x8 k0 = *(const bf16x8*)&Ks[(kt * 16 + fr) * SKK + fk];
        bf16x8 k1 = *(const bf16x8*)&Ks[(kt * 16 + fr) * SKK + 32 + fk];
        st[kt] = mfma16(k1, aq[qt][1], mfma16(k0, aq[qt][0], (f32x4){0.f, 0.f, 0.f, 0.f}));
      }

      // exp + diagonal mask + P^T write (b64: 4 consecutive keys per lane)
#pragma unroll
      for (int kt = 0; kt < 8; ++kt) {
        if (kt < lo || kt > hi) continue;
        const bool dL = (ch == 0) && (kt == lo);
        const bool dR = (ch == 2) && (kt == hi);
        bf16x4 pk;
#pragma unroll
        for (int r = 0; r < 4; ++r) {
          float p = exp2f(st[kt][r] * CEXP);
          int kl = quad * 4 + r;     // key within tile; q within tile = fr
          if (dL) p = (kl >= fr) ? p : 0.f;
          if (dR) p = (kl <= fr) ? p : 0.f;
          lrow[qt] += p;
          pk[r] = (bf16_t)p;
        }
        *(bf16x4*)&PsT[w][fr * PST + kt * 16 + quad * 4] = pk;
      }
      // zero-fill the single read-but-unwritten tile on edge chunks
      if ((ch == 0) && (lo & 1)) {
        bf16x4 zz; zz[0] = zz[1] = zz[2] = zz[3] = (bf16_t)0.f;
        *(bf16x4*)&PsT[w][fr * PST + (lo - 1) * 16 + quad * 4] = zz;
      }
      if ((ch == 2) && !(hi & 1)) {
        bf16x4 zz; zz[0] = zz[1] = zz[2] = zz[3] = (bf16_t)0.f;
        *(bf16x4*)&PsT[w][fr * PST + (hi + 1) * 16 + quad * 4] = zz;
      }

      // O += P V  (A = P [m=q=fr, k=key], B = V [n=dv=fr, k=key])
      const int pl = lo >> 1, ph = hi >> 1;
#pragma unroll
      for (int ks = 0; ks < 4; ++ks) {
        if (ks < pl || ks > ph) continue;
        bf16x8 pa = *(const bf16x8*)&PsT[w][fr * PST + ks * 32 + fk];
#pragma unroll
        for (int dt = 0; dt < 4; ++dt) {
          bf16x8 bv = *(const bf16x8*)&Vs[(dt * 16 + fr) * SVS + ks * 32 + fk];
          o[qt][dt] = mfma16(pa, bv, o[qt][dt]);
        }
      }
    }
  }

  // finish row sums: reduce over quads, then redistribute to O's row indexing
#pragma unroll
  for (int qt = 0; qt < 2; ++qt) {
    lrow[qt] += __shfl_xor(lrow[qt], 16, 64);
    lrow[qt] += __shfl_xor(lrow[qt], 32, 64);
  }
  float ln[2][4];
#pragma unroll
  for (int qt = 0; qt < 2; ++qt)
#pragma unroll
    for (int r = 0; r < 4; ++r)
      ln[qt][r] = __shfl(lrow[qt], quad * 4 + r, 64);

#pragma unroll
  for (int qt = 0; qt < 2; ++qt)
#pragma unroll
    for (int dt = 0; dt < 4; ++dt)
#pragma unroll
      for (int r = 0; r < 4; ++r) {
        float ov = o[qt][dt][r] / ln[qt][r];
        int srow = n * 128 + w * 32 + qt * 16 + quad * 4 + r;
        ctx[((size_t)b * 8192 + srow) * 1024 + h * 64 + dt * 16 + fr] = (bf16_t)ov;
      }
}

// ---------------- launch ----------------
extern "C" void kernel_launch(void* const* d_in, const int* in_sizes, int n_in,
                              void* d_out, int out_size, void* d_ws, size_t ws_size,
                              hipStream_t stream) {
  const float* x  = (const float*)d_in[0];
  const float* Wq = (const float*)d_in[1];
  const float* Wk = (const float*)d_in[2];
  const float* Wv = (const float*)d_in[3];
  const float* Wo = (const float*)d_in[4];
  float* out = (float*)d_out;

  char* p = (char*)d_ws;
  bf16_t* xb    = (bf16_t*)p; p += (size_t)16384 * 1024 * 2;
  bf16_t* WqkvT = (bf16_t*)p; p += (size_t)3 * 1024 * 1024 * 2;
  bf16_t* WoT   = (bf16_t*)p; p += (size_t)1024 * 1024 * 2;
  bf16_t* qhb   = (bf16_t*)p; p += (size_t)16384 * 1024 * 2;
  bf16_t* khb   = (bf16_t*)p; p += (size_t)16384 * 1024 * 2;
  bf16_t* vT2   = (bf16_t*)p; p += (size_t)16384 * 1024 * 2;
  bf16_t* ctx   = (bf16_t*)p; p += (size_t)16384 * 1024 * 2;

  prep<<<12288, 256, 0, stream>>>(x, Wq, Wk, Wv, Wo, xb, WqkvT,
                                  WqkvT + (size_t)1024 * 1024,
                                  WqkvT + (size_t)2 * 1024 * 1024, WoT);
  gemm_qkv<<<dim3(24, 128), 256, 0, stream>>>(xb, WqkvT, qhb, khb, vT2);
  swa<<<dim3(64, 16, 2), 256, 0, stream>>>(qhb, khb, vT2, ctx);
  gemm_bt<<<dim3(8, 128), 256, 0, stream>>>(ctx, WoT, out, 16384, 1024, 1024);
}

// Round 5
// 365.498 us; speedup vs baseline: 1.3825x; 1.0297x over previous
//
#include <hip/hip_runtime.h>

// B=2, S=8192, D=1024, H=16, DK=DV=64, W=Bq=128, nb=64.
// Pipeline: prep(cvt x->bf16 + 4x weight transpose) ;
//           gemm_qkv (fused N=3072, BK=64 two-plane LDS, epilogue scatters q/k per-head
//                     + V transposed tiles) ;
//           swa (S^T-form MFMA, no-max softmax, 2 barriers/chunk, VGPR prefetch) ;
//           gemm_bt (out proj, BK=64, fp32 out).
// ws: xb 33.5 + WqkvT 6.3 + WoT 2.1 + qh 33.5 + kh 33.5 + vT2 33.5 + ctx 33.5 = 176MB

typedef __bf16 bf16_t;
typedef bf16_t bf16x8 __attribute__((ext_vector_type(8)));
typedef bf16_t bf16x4 __attribute__((ext_vector_type(4)));
typedef float f32x4 __attribute__((ext_vector_type(4)));

#define CEXP 0.18033688011112042f  // 0.125 * log2(e)

__device__ __forceinline__ f32x4 mfma16(bf16x8 a, bf16x8 b, f32x4 c) {
  return __builtin_amdgcn_mfma_f32_16x16x32_bf16(a, b, c, 0, 0, 0);
}

#define GLL16(gptr, lptr)                                                     \
  __builtin_amdgcn_global_load_lds(                                           \
      (__attribute__((address_space(1))) void*)(gptr),                        \
      (__attribute__((address_space(3))) void*)(lptr), 16, 0, 0)

// ---------------- prep: x fp32->bf16 (blocks 0..8191) + weight transpose (8192..12287)
__global__ __launch_bounds__(256) void prep(const float* __restrict__ x,
                                            const float* __restrict__ W0,
                                            const float* __restrict__ W1,
                                            const float* __restrict__ W2,
                                            const float* __restrict__ W3,
                                            bf16_t* __restrict__ xb,
                                            bf16_t* T0, bf16_t* T1,
                                            bf16_t* T2, bf16_t* T3) {
  __shared__ float tile[32][33];
  const int t = threadIdx.x;
  if (blockIdx.x < 8192) {
    int i = blockIdx.x * 256 + t;
    f32x4 a = *(const f32x4*)&x[(size_t)i * 8];
    f32x4 b = *(const f32x4*)&x[(size_t)i * 8 + 4];
    bf16x8 o;
#pragma unroll
    for (int j = 0; j < 4; ++j) { o[j] = (bf16_t)a[j]; o[4 + j] = (bf16_t)b[j]; }
    *(bf16x8*)&xb[(size_t)i * 8] = o;
    return;
  }
  int wb = blockIdx.x - 8192;
  int z = wb >> 10, rem = wb & 1023;
  int bx = rem & 31, by = rem >> 5;
  const float* W; bf16_t* T;
  switch (z) {
    case 0: W = W0; T = T0; break;
    case 1: W = W1; T = T1; break;
    case 2: W = W2; T = T2; break;
    default: W = W3; T = T3; break;
  }
  int tx = t & 31, ty = t >> 5;
  int xc = bx * 32 + tx;
  int y0 = by * 32;
#pragma unroll
  for (int i = ty; i < 32; i += 8) tile[i][tx] = W[(size_t)(y0 + i) * 1024 + xc];
  __syncthreads();
  int xo = y0 + tx;
  int yo = bx * 32;
#pragma unroll
  for (int i = ty; i < 32; i += 8)
    T[(size_t)(yo + i) * 1024 + xo] = (bf16_t)tile[tx][i];
}

// ---------------- fused QKV GEMM: xb[16384,1024] x WqkvT[3072,1024]^T -------------
// BK=64 staged as two 128x32 planes per operand (keeps m97 bank/GLL16 layout,
// halves barrier frequency). Epilogue: cols 0..1023 -> qh[b,h,s,64];
// 1024..2047 -> kh; 2048..3071 -> vT2 tiles [bh][sblk=s/16][dv][16s].
__global__ __launch_bounds__(256) void gemm_qkv(const bf16_t* __restrict__ A,
                                                const bf16_t* __restrict__ Bt,
                                                bf16_t* __restrict__ qh,
                                                bf16_t* __restrict__ kh,
                                                bf16_t* __restrict__ vT2) {
  __shared__ bf16_t As0[128 * 32];
  __shared__ bf16_t As1[128 * 32];
  __shared__ bf16_t Bs0[128 * 32];
  __shared__ bf16_t Bs1[128 * 32];
  const int t = threadIdx.x;
  const int K = 1024;
  const int m0 = blockIdx.y << 7, n0 = blockIdx.x << 7;
  const int ar = t >> 2, ac = (t & 3) << 3;
  const bf16_t* Ag = A + (size_t)(m0 + ar) * K + ac;
  const bf16_t* Bg = Bt + (size_t)(n0 + ar) * K + ac;
  const size_t step64 = (size_t)64 * K;
  const int lane = t & 63;
  const int wm = ((t >> 7) & 1) << 6;
  const int wn = ((t >> 6) & 1) << 6;
  const int fr = lane & 15, quad = lane >> 4, fk = quad << 3;

  f32x4 acc[4][4] = {};
  for (int k0 = 0; k0 < K; k0 += 64) {
    GLL16(Ag + k0, &As0[ar * 32 + ac]);
    GLL16(Ag + step64 + k0, &As0[(ar + 64) * 32 + ac]);
    GLL16(Ag + k0 + 32, &As1[ar * 32 + ac]);
    GLL16(Ag + step64 + k0 + 32, &As1[(ar + 64) * 32 + ac]);
    GLL16(Bg + k0, &Bs0[ar * 32 + ac]);
    GLL16(Bg + step64 + k0, &Bs0[(ar + 64) * 32 + ac]);
    GLL16(Bg + k0 + 32, &Bs1[ar * 32 + ac]);
    GLL16(Bg + step64 + k0 + 32, &Bs1[(ar + 64) * 32 + ac]);
    __syncthreads();
#pragma unroll
    for (int hh = 0; hh < 2; ++hh) {
      const bf16_t* Asp = hh ? As1 : As0;
      const bf16_t* Bsp = hh ? Bs1 : Bs0;
      bf16x8 af[4], bfv[4];
#pragma unroll
      for (int i = 0; i < 4; ++i) af[i] = *(const bf16x8*)&Asp[(wm + i * 16 + fr) * 32 + fk];
#pragma unroll
      for (int j = 0; j < 4; ++j) bfv[j] = *(const bf16x8*)&Bsp[(wn + j * 16 + fr) * 32 + fk];
#pragma unroll
      for (int i = 0; i < 4; ++i)
#pragma unroll
        for (int j = 0; j < 4; ++j) acc[i][j] = mfma16(af[i], bfv[j], acc[i][j]);
    }
    __syncthreads();
  }

  const int colbase = n0 + wn;           // multiple of 64 -> single head per wave-half
  if (colbase < 2048) {
    bf16_t* dst = (colbase < 1024) ? qh : kh;
    const int cb = colbase & 1023;
#pragma unroll
    for (int i = 0; i < 4; ++i)
#pragma unroll
      for (int j = 0; j < 4; ++j) {
        int col = cb + j * 16 + fr;
        int h = col >> 6, dk = col & 63;
#pragma unroll
        for (int r = 0; r < 4; ++r) {
          int cm = m0 + wm + i * 16 + quad * 4 + r;
          int b = cm >> 13, s = cm & 8191;
          dst[((((size_t)(b * 16 + h) << 13) | s) << 6) | dk] = (bf16_t)acc[i][j][r];
        }
      }
  } else {
    const int cb = colbase - 2048;
#pragma unroll
    for (int i = 0; i < 4; ++i) {
      int s0 = m0 + wm + i * 16;
      int b = s0 >> 13, sblk = (s0 & 8191) >> 4;
#pragma unroll
      for (int j = 0; j < 4; ++j) {
        int col = cb + j * 16;
        int h = col >> 6, dv = (col & 63) + fr;
        bf16x4 pk;
#pragma unroll
        for (int r = 0; r < 4; ++r) pk[r] = (bf16_t)acc[i][j][r];
        *(bf16x4*)&vT2[((size_t)(b * 16 + h) * 512 + sblk) * 1024 + dv * 16 + quad * 4] = pk;
      }
    }
  }
}

// ---------------- GEMM: A[M,K] bf16 x Bt[N,K] bf16 -> C fp32 (out proj), BK=64 ----
__global__ __launch_bounds__(256) void gemm_bt(const bf16_t* __restrict__ A,
                                               const bf16_t* __restrict__ Bt,
                                               float* __restrict__ Cf,
                                               int M, int N, int K) {
  __shared__ bf16_t As0[128 * 32];
  __shared__ bf16_t As1[128 * 32];
  __shared__ bf16_t Bs0[128 * 32];
  __shared__ bf16_t Bs1[128 * 32];
  const int t = threadIdx.x;
  const int m0 = blockIdx.y << 7, n0 = blockIdx.x << 7;
  const int ar = t >> 2, ac = (t & 3) << 3;
  const bf16_t* Ag = A + (size_t)(m0 + ar) * K + ac;
  const bf16_t* Bg = Bt + (size_t)(n0 + ar) * K + ac;
  const size_t step64 = (size_t)64 * K;
  const int lane = t & 63;
  const int wm = ((t >> 7) & 1) << 6;
  const int wn = ((t >> 6) & 1) << 6;
  const int fr = lane & 15, fk = (lane >> 4) << 3;

  f32x4 acc[4][4] = {};
  for (int k0 = 0; k0 < K; k0 += 64) {
    GLL16(Ag + k0, &As0[ar * 32 + ac]);
    GLL16(Ag + step64 + k0, &As0[(ar + 64) * 32 + ac]);
    GLL16(Ag + k0 + 32, &As1[ar * 32 + ac]);
    GLL16(Ag + step64 + k0 + 32, &As1[(ar + 64) * 32 + ac]);
    GLL16(Bg + k0, &Bs0[ar * 32 + ac]);
    GLL16(Bg + step64 + k0, &Bs0[(ar + 64) * 32 + ac]);
    GLL16(Bg + k0 + 32, &Bs1[ar * 32 + ac]);
    GLL16(Bg + step64 + k0 + 32, &Bs1[(ar + 64) * 32 + ac]);
    __syncthreads();
#pragma unroll
    for (int hh = 0; hh < 2; ++hh) {
      const bf16_t* Asp = hh ? As1 : As0;
      const bf16_t* Bsp = hh ? Bs1 : Bs0;
      bf16x8 af[4], bfv[4];
#pragma unroll
      for (int i = 0; i < 4; ++i) af[i] = *(const bf16x8*)&Asp[(wm + i * 16 + fr) * 32 + fk];
#pragma unroll
      for (int j = 0; j < 4; ++j) bfv[j] = *(const bf16x8*)&Bsp[(wn + j * 16 + fr) * 32 + fk];
#pragma unroll
      for (int i = 0; i < 4; ++i)
#pragma unroll
        for (int j = 0; j < 4; ++j) acc[i][j] = mfma16(af[i], bfv[j], acc[i][j]);
    }
    __syncthreads();
  }
#pragma unroll
  for (int i = 0; i < 4; ++i)
#pragma unroll
    for (int j = 0; j < 4; ++j)
#pragma unroll
      for (int r = 0; r < 4; ++r) {
        int cm = m0 + wm + i * 16 + ((lane >> 4) << 2) + r;
        int cn = n0 + wn + j * 16 + fr;
        Cf[(size_t)cm * N + cn] = acc[i][j][r];
      }
}

// ---------------- sliding-window attention ----------------
// qh/kh: [b*16+h][8192][64]; vT2: [b*16+h][512 sblk][64 dv][16 s].
// S^T = K Q^T form; P^T b64 stores; 2 barriers/chunk; K/V prefetched into VGPRs.
#define SKK 72    // K tile stride (64+8)
#define SVS 136   // Vs stride (128+8)
#define PST 136   // PsT stride (128+8)

__global__ __launch_bounds__(256, 3) void swa(const bf16_t* __restrict__ qh,
                                              const bf16_t* __restrict__ kh,
                                              const bf16_t* __restrict__ vT2,
                                              bf16_t* __restrict__ ctx) {
  __shared__ bf16_t Ks[128 * SKK];       // 18.4 KB [key][dk]
  __shared__ bf16_t Vs[64 * SVS];        // 17.4 KB [dv][key]
  __shared__ bf16_t PsT[4][16 * PST];    // 17.4 KB per-wave P^T [q16][key]

  const int t = threadIdx.x, lane = t & 63, w = t >> 6;
  const int n = blockIdx.x, h = blockIdx.y, b = blockIdx.z;
  const int fr = lane & 15, quad = lane >> 4, fk = quad << 3;
  const size_t bh = (size_t)(b * 16 + h);

  // Q fragments (B-operand: n=q=fr, k=dk=quad*8+j)
  bf16x8 aq[2][2];
  {
    const size_t qbase = (bh * 8192 + n * 128 + w * 32) * 64;
#pragma unroll
    for (int qt = 0; qt < 2; ++qt)
#pragma unroll
      for (int ks = 0; ks < 2; ++ks)
        aq[qt][ks] = *(const bf16x8*)&qh[qbase + (size_t)(qt * 16 + fr) * 64 + ks * 32 + fk];
  }

  bf16x8 kr[4], vr[4];
  auto loadKV = [&](int kn) {
#pragma unroll
    for (int it = 0; it < 4; ++it) {
      int c = it * 256 + t;
      kr[it] = *(const bf16x8*)&kh[(bh * 8192 + kn * 128 + (c >> 3)) * 64 + ((c & 7) << 3)];
      int sb = c >> 7, dv = (c & 127) >> 1, sh = c & 1;
      vr[it] = *(const bf16x8*)&vT2[(bh * 512 + kn * 8 + sb) * 1024 + dv * 16 + sh * 8];
    }
  };

  const int cbeg = (n == 0) ? 1 : 0;
  const int cend = (n == 63) ? 1 : 2;
  loadKV(n + cbeg - 1);

  float lrow[2] = {0.f, 0.f};
  f32x4 o[2][4] = {};   // C-layout O[q][dv]: col dv = fr, row q = quad*4+r (+16*qt)

  for (int ch = cbeg; ch <= cend; ++ch) {
    __syncthreads();   // waves done reading Ks/Vs of prev chunk; drains prefetch vmcnt
#pragma unroll
    for (int it = 0; it < 4; ++it) {
      int c = it * 256 + t;
      *(bf16x8*)&Ks[(c >> 3) * SKK + ((c & 7) << 3)] = kr[it];
      int sb = c >> 7, dv = (c & 127) >> 1, sh = c & 1;
      *(bf16x8*)&Vs[dv * SVS + sb * 16 + sh * 8] = vr[it];
    }
    __syncthreads();   // cheap: lgkm only, VM queue empty
    if (ch < cend) loadKV(n + ch);   // next chunk's loads fly during compute

#pragma unroll
    for (int qt = 0; qt < 2; ++qt) {
      const int lo = (ch == 0) ? 2 * w + qt : 0;
      const int hi = (ch == 2) ? 2 * w + qt : 7;

      // S^T tiles: D[key][q], A = K (m=key=fr, k=dk), B = Q
      f32x4 st[8];
#pragma unroll
      for (int kt = 0; kt < 8; ++kt) {
        if (kt < lo || kt > hi) continue;
        bf16x8 k0 = *(const bf16x8*)&Ks[(kt * 16 + fr) * SKK + fk];
        bf16x8 k1 = *(const bf16x8*)&Ks[(kt * 16 + fr) * SKK + 32 + fk];
        st[kt] = mfma16(k1, aq[qt][1], mfma16(k0, aq[qt][0], (f32x4){0.f, 0.f, 0.f, 0.f}));
      }

      // exp + diagonal mask + P^T write (b64: 4 consecutive keys per lane)
#pragma unroll
      for (int kt = 0; kt < 8; ++kt) {
        if (kt < lo || kt > hi) continue;
        const bool dL = (ch == 0) && (kt == lo);
        const bool dR = (ch == 2) && (kt == hi);
        bf16x4 pk;
#pragma unroll
        for (int r = 0; r < 4; ++r) {
          float p = exp2f(st[kt][r] * CEXP);
          int kl = quad * 4 + r;     // key within tile; q within tile = fr
          if (dL) p = (kl >= fr) ? p : 0.f;
          if (dR) p = (kl <= fr) ? p : 0.f;
          lrow[qt] += p;
          pk[r] = (bf16_t)p;
        }
        *(bf16x4*)&PsT[w][fr * PST + kt * 16 + quad * 4] = pk;
      }
      // zero-fill the single read-but-unwritten tile on edge chunks
      if ((ch == 0) && (lo & 1)) {
        bf16x4 zz; zz[0] = zz[1] = zz[2] = zz[3] = (bf16_t)0.f;
        *(bf16x4*)&PsT[w][fr * PST + (lo - 1) * 16 + quad * 4] = zz;
      }
      if ((ch == 2) && !(hi & 1)) {
        bf16x4 zz; zz[0] = zz[1] = zz[2] = zz[3] = (bf16_t)0.f;
        *(bf16x4*)&PsT[w][fr * PST + (hi + 1) * 16 + quad * 4] = zz;
      }

      // O += P V  (A = P [m=q=fr, k=key], B = V [n=dv=fr, k=key])
      const int pl = lo >> 1, ph = hi >> 1;
#pragma unroll
      for (int ks = 0; ks < 4; ++ks) {
        if (ks < pl || ks > ph) continue;
        bf16x8 pa = *(const bf16x8*)&PsT[w][fr * PST + ks * 32 + fk];
#pragma unroll
        for (int dt = 0; dt < 4; ++dt) {
          bf16x8 bv = *(const bf16x8*)&Vs[(dt * 16 + fr) * SVS + ks * 32 + fk];
          o[qt][dt] = mfma16(pa, bv, o[qt][dt]);
        }
      }
    }
  }

  // finish row sums: reduce over quads, then redistribute to O's row indexing
#pragma unroll
  for (int qt = 0; qt < 2; ++qt) {
    lrow[qt] += __shfl_xor(lrow[qt], 16, 64);
    lrow[qt] += __shfl_xor(lrow[qt], 32, 64);
  }
  float ln[2][4];
#pragma unroll
  for (int qt = 0; qt < 2; ++qt)
#pragma unroll
    for (int r = 0; r < 4; ++r)
      ln[qt][r] = __shfl(lrow[qt], quad * 4 + r, 64);

#pragma unroll
  for (int qt = 0; qt < 2; ++qt)
#pragma unroll
    for (int dt = 0; dt < 4; ++dt)
#pragma unroll
      for (int r = 0; r < 4; ++r) {
        float ov = o[qt][dt][r] / ln[qt][r];
        int srow = n * 128 + w * 32 + qt * 16 + quad * 4 + r;
        ctx[((size_t)b * 8192 + srow) * 1024 + h * 64 + dt * 16 + fr] = (bf16_t)ov;
      }
}

// ---------------- launch ----------------
extern "C" void kernel_launch(void* const* d_in, const int* in_sizes, int n_in,
                              void* d_out, int out_size, void* d_ws, size_t ws_size,
                              hipStream_t stream) {
  const float* x  = (const float*)d_in[0];
  const float* Wq = (const float*)d_in[1];
  const float* Wk = (const float*)d_in[2];
  const float* Wv = (const float*)d_in[3];
  const float* Wo = (const float*)d_in[4];
  float* out = (float*)d_out;

  char* p = (char*)d_ws;
  bf16_t* xb    = (bf16_t*)p; p += (size_t)16384 * 1024 * 2;
  bf16_t* WqkvT = (bf16_t*)p; p += (size_t)3 * 1024 * 1024 * 2;
  bf16_t* WoT   = (bf16_t*)p; p += (size_t)1024 * 1024 * 2;
  bf16_t* qhb   = (bf16_t*)p; p += (size_t)16384 * 1024 * 2;
  bf16_t* khb   = (bf16_t*)p; p += (size_t)16384 * 1024 * 2;
  bf16_t* vT2   = (bf16_t*)p; p += (size_t)16384 * 1024 * 2;
  bf16_t* ctx   = (bf16_t*)p; p += (size_t)16384 * 1024 * 2;

  prep<<<12288, 256, 0, stream>>>(x, Wq, Wk, Wv, Wo, xb, WqkvT,
                                  WqkvT + (size_t)1024 * 1024,
                                  WqkvT + (size_t)2 * 1024 * 1024, WoT);
  gemm_qkv<<<dim3(24, 128), 256, 0, stream>>>(xb, WqkvT, qhb, khb, vT2);
  swa<<<dim3(64, 16, 2), 256, 0, stream>>>(qhb, khb, vT2, ctx);
  gemm_bt<<<dim3(8, 128), 256, 0, stream>>>(ctx, WoT, out, 16384, 1024, 1024);
}